// Round 5
// baseline (394.929 us; speedup 1.0000x reference)
//
#include <hip/hip_runtime.h>
#include <math.h>

#define HH 2048
#define WW 2048
#define TT 11
constexpr long long HW = (long long)HH * WW;

struct MMat { float m[TT][TT]; };

__device__ __forceinline__ float4 ld4(const float* p) { return *(const float4*)p; }

// ---------------- phy kernel ----------------
// R8: R4 per-wave structure (1 row/thread, 2-deep pipeline, ~56 VGPR) with
// two scheduling changes:
//  (a) __launch_bounds__(256,6): 6 blocks/CU = 24 waves/CU (was 12) -- the
//      counters across R4/R6/R7 show a latency-bound invariant (~126 us with
//      VALU 22%, HBM 27%, occ 28-39%); double the resident waves per SIMD.
//  (b) grid (512,9) + XCD-chunk swizzle rg=(rx&7)*64+(rx>>3). 512%8==0 so
//      xcd == rx&7 exactly: each XCD owns a contiguous 256-row band and
//      walks it sequentially for all 9 col-windows. Halo rows (shared by
//      adjacent row-blocks) become XCD-local L2 hits instead of cross-die
//      reads, and each XCD's HBM fetch stream is contiguous.
// Tripwire: WRITE_SIZE must stay ~144 KB (R5 scratch lesson).
__global__ __launch_bounds__(256, 6) void phy_kernel(const float* __restrict__ u,
                                                     const float* __restrict__ f1,
                                                     MMat M,
                                                     float* __restrict__ ws)
{
    const int lane = threadIdx.x;              // 0..63
    const int ty   = threadIdx.y;              // 0..3
    const int rx   = blockIdx.x;               // 0..511 row-group (swizzled)
    const int rg   = (rx & 7) * 64 + (rx >> 3);// XCD-banded row group
    const int bw   = blockIdx.y;               // 0..8 col window
    int w0 = bw * 252; if (w0 > WW - 256) w0 = WW - 256;   // aligned window start
    const int lo = bw * 252 + 1;               // first output col of this window
    int hi = bw * 252 + 252; if (hi > WW - 2) hi = WW - 2; // last output col

    const int h    = 1 + rg * 4 + ty;          // 1..2048
    const int heff = (h > HH - 2) ? (HH - 2) : h;
    const float rowmask = (h <= HH - 2) ? 1.0f : 0.0f;

    const int col0 = w0 + lane * 4;            // absolute col of element .x
    float4 mask;
    {
        int c0 = col0, c1 = col0 + 1, c2 = col0 + 2, c3 = col0 + 3;
        mask.x = (c0 >= lo && c0 <= hi) ? rowmask : 0.0f;
        mask.y = (c1 >= lo && c1 <= hi) ? rowmask : 0.0f;
        mask.z = (c2 >= lo && c2 <= hi) ? rowmask : 0.0f;
        mask.w = (c3 >= lo && c3 <= hi) ? rowmask : 0.0f;
    }

    const long long rowm = (long long)(heff - 1) * WW + col0;
    const long long row0 = (long long)heff * WW + col0;
    const long long rowp = (long long)(heff + 1) * WW + col0;

    const float c0f = 0.34520446044393f;
    const float c1f = 0.309591078922457f;
    const float c2f = -2.619182157203629f;
    const float kod = 0.01f * 4194304.0f;   // KAPPA / DX^2

    float4 D[TT];
    #pragma unroll
    for (int t = 0; t < TT; ++t) D[t] = make_float4(0.f, 0.f, 0.f, 0.f);

    float acc = 0.0f;

    // pipeline prologue: slice 0 loads in flight
    float4 vm_n = ld4(u + rowm);
    float4 v0_n = ld4(u + row0);
    float4 vp_n = ld4(u + rowp);
    float4 fv_n = ld4(f1 + row0);

    #pragma unroll
    for (int s = 0; s < TT; ++s) {
        const float4 vm = vm_n;
        const float4 v0 = v0_n;
        const float4 vp = vp_n;
        const float4 fv = fv_n;

        // issue next slice's loads BEFORE consuming this slice
        if (s + 1 < TT) {
            const float* un = u + (long long)(s + 1) * HW;
            vm_n = ld4(un + rowm);
            v0_n = ld4(un + row0);
            vp_n = ld4(un + rowp);
            fv_n = ld4(f1 + (long long)(s + 1) * HW + row0);
        }

        // in-wave horizontal neighbors (window pos 0 / 255 never output -> garbage safe)
        const float lm = __shfl_up(vm.w, 1);
        const float l0 = __shfl_up(v0.w, 1);
        const float lp = __shfl_up(vp.w, 1);
        const float rm = __shfl_down(vm.x, 1);
        const float r0 = __shfl_down(v0.x, 1);
        const float rp = __shfl_down(vp.x, 1);

        float4 lap;
        lap.x = c0f * ((lm   + vm.y) + (lp   + vp.y)) + c1f * ((vm.x + vp.x) + (l0   + v0.y)) + c2f * v0.x;
        lap.y = c0f * ((vm.x + vm.z) + (vp.x + vp.z)) + c1f * ((vm.y + vp.y) + (v0.x + v0.z)) + c2f * v0.y;
        lap.z = c0f * ((vm.y + vm.w) + (vp.y + vp.w)) + c1f * ((vm.z + vp.z) + (v0.y + v0.w)) + c2f * v0.z;
        lap.w = c0f * ((vm.z + rm  ) + (vp.z + rp  )) + c1f * ((vm.w + vp.w) + (v0.z + r0  )) + c2f * v0.w;

        // fu[s] = D[s] (partials s'<s) + M[s][s]*u_s + (u_s - kod*lap - f1)
        const float mss = M.m[s][s];
        float fx = (D[s].x + mss * v0.x + (v0.x - kod * lap.x - fv.x)) * mask.x;
        float fy = (D[s].y + mss * v0.y + (v0.y - kod * lap.y - fv.y)) * mask.y;
        float fz = (D[s].z + mss * v0.z + (v0.z - kod * lap.z - fv.z)) * mask.z;
        float fw = (D[s].w + mss * v0.w + (v0.w - kod * lap.w - fv.w)) * mask.w;
        acc += fx * fx + fy * fy + fz * fz + fw * fw;

        #pragma unroll
        for (int t = s + 1; t < TT; ++t) {
            const float m = M.m[t][s];
            D[t].x += m * v0.x;
            D[t].y += m * v0.y;
            D[t].z += m * v0.z;
            D[t].w += m * v0.w;
        }
    }

    // 3-level reduction: wave shuffle -> LDS -> one atomic per block
    #pragma unroll
    for (int off = 32; off > 0; off >>= 1)
        acc += __shfl_down(acc, off, 64);
    __shared__ float wsum[4];
    const int tid = ty * 64 + lane;
    const int wid = tid >> 6;
    if (lane == 0) wsum[wid] = acc;
    __syncthreads();
    if (tid == 0) {
        float s = (wsum[0] + wsum[1]) + (wsum[2] + wsum[3]);
        atomicAdd(&ws[0], s);
    }
}

// ---------------- bc kernel: boundary loss ----------------
__global__ __launch_bounds__(256) void bc_kernel(const float* __restrict__ u,
                                                 float* __restrict__ ws)
{
    int idx = blockIdx.x * 256 + threadIdx.x;   // 0 .. 10*2048-1
    float acc = 0.0f;
    if (idx < 10 * 2048) {
        int i = idx >> 11;       // time index 0..9 (u slice i+1)
        int j = idx & 2047;
        float tval = 0.1f + 0.1f * (float)i;
        float xj = (float)j * (1.0f / 2047.0f);
        float x1 = powf(tval, 1.5f) * sinf(6.283185307179586f * xj);
        const float* ub = u + (long long)(i + 1) * HW;
        float l = ub[(long long)j * WW + 0]        - x1;
        float r = ub[(long long)j * WW + (WW - 1)] - x1;
        float tp = ub[j]                            - x1;
        float bt = ub[(long long)(HH - 1) * WW + j] - x1;
        acc = l * l + r * r + tp * tp + bt * bt;
    }
    #pragma unroll
    for (int off = 32; off > 0; off >>= 1)
        acc += __shfl_down(acc, off, 64);
    __shared__ float wsum[4];
    int tid = threadIdx.x;
    int lane = tid & 63, wid = tid >> 6;
    if (lane == 0) wsum[wid] = acc;
    __syncthreads();
    if (tid == 0) {
        float s = (wsum[0] + wsum[1]) + (wsum[2] + wsum[3]);
        atomicAdd(&ws[1], s);
    }
}

// ---------------- finalize ----------------
__global__ void fin_kernel(const float* __restrict__ ws, float* __restrict__ out)
{
    out[0] = ws[0] * (2.0f / (11.0f * 2046.0f * 2046.0f));
    out[1] = ws[1] * (1.0f / (10.0f * 2048.0f * 2048.0f));
}

static MMat make_M()
{
    double w[10];
    w[0] = 1.0;
    for (int j = 1; j <= 9; ++j)
        w[j] = pow((double)j + 1.0, 0.5) - pow((double)j, 0.5);
    double M[TT][TT] = {};
    for (int i = 1; i < TT; ++i) {
        M[i][i] = w[0];
        M[i][0] -= w[i - 1];
        for (int k = 1; k < i; ++k)
            M[i][k] = -(w[i - k - 1] - w[i - k]);
    }
    double pref = pow(0.1, -0.5) / 0.886226925452758;
    MMat r;
    for (int i = 0; i < TT; ++i)
        for (int j = 0; j < TT; ++j)
            r.m[i][j] = (float)(pref * M[i][j]);
    return r;
}

extern "C" void kernel_launch(void* const* d_in, const int* in_sizes, int n_in,
                              void* d_out, int out_size, void* d_ws, size_t ws_size,
                              hipStream_t stream)
{
    const float* u  = (const float*)d_in[0];
    const float* f1 = (const float*)d_in[1];
    float* out = (float*)d_out;
    float* ws  = (float*)d_ws;

    MMat M = make_M();

    hipMemsetAsync(ws, 0, 2 * sizeof(float), stream);

    dim3 block(64, 4);
    dim3 grid(512, 9);   // x = row-groups (XCD-swizzled), y = 9 col-windows
    phy_kernel<<<grid, block, 0, stream>>>(u, f1, M, ws);

    bc_kernel<<<(10 * 2048 + 255) / 256, 256, 0, stream>>>(u, ws);

    fin_kernel<<<1, 1, 0, stream>>>(ws, out);
}